// Round 6
// baseline (109.815 us; speedup 1.0000x reference)
//
#include <hip/hip_runtime.h>
#include <hip/hip_bf16.h>

// RBF: out[n][o] = exp(-max(||x_n||^2 - 2<x_n,c_o> + ||c_o||^2, 0) * exp(-2*ls_o))
// M=131072, K=128, O=512.  Memory-bound: 67MB read + 268MB write -> ~55us floor.
//
// Round-5 = round-4 design with the nontemporal builtin type fix:
// __builtin_nontemporal_* requires native vector types (ext_vector_type),
// not HIP_vector_type<float,4>. Use f32x4 throughout.
//
//  K1: pack 512 centers fp32->bf16 into d_ws in MFMA-fragment order (8192 x 16B,
//      fully coalesced loads in K2) + fused exp(-2ls), csq*exp(-2ls) tables.
//  K2: 1024 blocks x 256 threads (4 waves), ZERO LDS, ZERO barriers, 4 blocks/CU.
//      Each wave owns 32 x-rows (2 x 16-row MFMA tiles): x -> bf16 register
//      fragments (nontemporal loads), then 32 groups of 16 centers with explicit
//      double-buffered fragment prefetch from L2-resident ws. A=centers, B=x so
//      each lane's 4 accs are 4 consecutive output cols of one row -> f32x4
//      nontemporal stores. x/out marked nontemporal so L2 keeps the frag table.

typedef __attribute__((ext_vector_type(8))) short bf16x8;
typedef __attribute__((ext_vector_type(4))) float f32x4;
typedef __attribute__((ext_vector_type(4))) unsigned u32x4;

#define KDIM 128
#define ODIM 512

union BF8 { unsigned u[4]; bf16x8 v; u32x4 q; };

// round-to-nearest-even fp32 -> bf16, packed pair
__device__ __forceinline__ unsigned pack_bf2(float a, float b) {
    unsigned ua = __builtin_bit_cast(unsigned, a);
    unsigned ub = __builtin_bit_cast(unsigned, b);
    ua += 0x7fffu + ((ua >> 16) & 1u);
    ub += 0x7fffu + ((ub >> 16) & 1u);
    return (ua >> 16) | (ub & 0xffff0000u);
}

// ---------------- K1: pack centers + tables into ws ----------------
// ws layout: [0,128KiB) frag region: u32x4 index (g*4+kk)*64+l holds bf16x8 of
//            center c=g*16+(l&15), k = kk*32+(l>>4)*8 .. +8
//            [128KiB, +2KiB) sIS = exp(-2*ls)   [130KiB, +2KiB) sCS = csq*sIS
__global__ __launch_bounds__(256) void rbf_pack_kernel(
    const float* __restrict__ centers,
    const float* __restrict__ log_sigmas,
    u32x4* __restrict__ wsfrag,
    float* __restrict__ wsis,
    float* __restrict__ wscs)
{
    const int b = blockIdx.x;
    if (b < 32) {
        int i  = b * 256 + threadIdx.x;      // 0..8191
        int g  = i >> 8;
        int kk = (i >> 6) & 3;
        int l  = i & 63;
        int c  = g * 16 + (l & 15);
        int k0 = kk * 32 + (l >> 4) * 8;
        const f32x4* p = (const f32x4*)(centers + (size_t)c * KDIM + k0);
        f32x4 v0 = p[0], v1 = p[1];
        BF8 w;
        w.u[0] = pack_bf2(v0.x, v0.y);
        w.u[1] = pack_bf2(v0.z, v0.w);
        w.u[2] = pack_bf2(v1.x, v1.y);
        w.u[3] = pack_bf2(v1.z, v1.w);
        wsfrag[i] = w.q;
    } else {
        int c = (b - 32) * 256 + threadIdx.x;   // 0..511
        const f32x4* p = (const f32x4*)(centers + (size_t)c * KDIM);
        float s = 0.f;
        #pragma unroll
        for (int k = 0; k < 32; ++k) {
            f32x4 v = p[k];
            s += v.x*v.x + v.y*v.y + v.z*v.z + v.w*v.w;
        }
        float a = __expf(-2.0f * log_sigmas[c]);
        wsis[c] = a;
        wscs[c] = s * a;
    }
}

// ---------------- K2: main streamer ----------------
__global__ __launch_bounds__(256, 4) void rbf_main_kernel(
    const float* __restrict__ x,
    const u32x4* __restrict__ wsfrag,
    const f32x4* __restrict__ wsis4,
    const f32x4* __restrict__ wscs4,
    float* __restrict__ out)
{
    const int t  = threadIdx.x;
    const int w  = t >> 6;
    const int l  = t & 63;
    const int lr = l & 15;
    const int lk = l >> 4;

    const int r0 = blockIdx.x * 128 + w * 32;

    // ---- x tiles -> bf16 register fragments (nontemporal: read-once) ----
    bf16x8 xf0[4], xf1[4];
    float xsq0, xsq1;
#define LOADX(XF, XS, ROWOFF)                                                  \
    {                                                                          \
        const float* xp = x + (size_t)(r0 + (ROWOFF) + lr) * KDIM + lk * 8;    \
        float s = 0.f;                                                         \
        _Pragma("unroll")                                                      \
        for (int kk = 0; kk < 4; ++kk) {                                       \
            const f32x4* p = (const f32x4*)(xp + kk * 32);                     \
            f32x4 v0 = __builtin_nontemporal_load(p);                          \
            f32x4 v1 = __builtin_nontemporal_load(p + 1);                      \
            s += v0.x*v0.x + v0.y*v0.y + v0.z*v0.z + v0.w*v0.w                 \
               + v1.x*v1.x + v1.y*v1.y + v1.z*v1.z + v1.w*v1.w;                \
            BF8 bw;                                                            \
            bw.u[0] = pack_bf2(v0.x, v0.y);                                    \
            bw.u[1] = pack_bf2(v0.z, v0.w);                                    \
            bw.u[2] = pack_bf2(v1.x, v1.y);                                    \
            bw.u[3] = pack_bf2(v1.z, v1.w);                                    \
            XF[kk] = bw.v;                                                     \
        }                                                                      \
        s += __shfl_xor(s, 16);                                                \
        s += __shfl_xor(s, 32);                                                \
        XS = s;                                                                \
    }
    LOADX(xf0, xsq0, 0)
    LOADX(xf1, xsq1, 16)
#undef LOADX

    float* orow0 = out + (size_t)(r0 + lr) * ODIM;
    float* orow1 = orow0 + (size_t)16 * ODIM;

    const bf16x8* fb = (const bf16x8*)wsfrag + l;   // + (g*4+kk)*64

    // preload group 0 fragments
    bf16x8 cfA[4], cfB[4];
    cfA[0] = fb[0];
    cfA[1] = fb[64];
    cfA[2] = fb[128];
    cfA[3] = fb[192];

    // one group: use CUR frags, prefetch group (g+1)&31 into NXT
#define STEP(G, CUR, NXT)                                                      \
    {                                                                          \
        const int gn = ((G) + 1) & 31;                                         \
        NXT[0] = fb[gn * 256 + 0];                                             \
        NXT[1] = fb[gn * 256 + 64];                                            \
        NXT[2] = fb[gn * 256 + 128];                                           \
        NXT[3] = fb[gn * 256 + 192];                                           \
        f32x4 a0 = (f32x4){0.f, 0.f, 0.f, 0.f};                                \
        f32x4 a1 = (f32x4){0.f, 0.f, 0.f, 0.f};                                \
        _Pragma("unroll")                                                      \
        for (int kk = 0; kk < 4; ++kk) {                                       \
            a0 = __builtin_amdgcn_mfma_f32_16x16x32_bf16(CUR[kk], xf0[kk], a0, 0, 0, 0); \
            a1 = __builtin_amdgcn_mfma_f32_16x16x32_bf16(CUR[kk], xf1[kk], a1, 0, 0, 0); \
        }                                                                      \
        const int gi = (G) * 4 + lk;                                           \
        f32x4 A4 = wsis4[gi];                                                  \
        f32x4 B4 = wscs4[gi];                                                  \
        f32x4 o0, o1;                                                          \
        o0.x = __expf(-fmaxf(fmaf(A4.x, fmaf(-2.f, a0[0], xsq0), B4.x), 0.f)); \
        o0.y = __expf(-fmaxf(fmaf(A4.y, fmaf(-2.f, a0[1], xsq0), B4.y), 0.f)); \
        o0.z = __expf(-fmaxf(fmaf(A4.z, fmaf(-2.f, a0[2], xsq0), B4.z), 0.f)); \
        o0.w = __expf(-fmaxf(fmaf(A4.w, fmaf(-2.f, a0[3], xsq0), B4.w), 0.f)); \
        o1.x = __expf(-fmaxf(fmaf(A4.x, fmaf(-2.f, a1[0], xsq1), B4.x), 0.f)); \
        o1.y = __expf(-fmaxf(fmaf(A4.y, fmaf(-2.f, a1[1], xsq1), B4.y), 0.f)); \
        o1.z = __expf(-fmaxf(fmaf(A4.z, fmaf(-2.f, a1[2], xsq1), B4.z), 0.f)); \
        o1.w = __expf(-fmaxf(fmaf(A4.w, fmaf(-2.f, a1[3], xsq1), B4.w), 0.f)); \
        const int cb = (G) * 16 + lk * 4;                                      \
        __builtin_nontemporal_store(o0, (f32x4*)(orow0 + cb));                 \
        __builtin_nontemporal_store(o1, (f32x4*)(orow1 + cb));                 \
    }

    #pragma unroll 2
    for (int g = 0; g < 32; g += 2) {
        STEP(g,     cfA, cfB)
        STEP(g + 1, cfB, cfA)
    }
#undef STEP
}

// ---------------- fallback (round-3 kernel, proven): used if ws too small ----
__global__ __launch_bounds__(1024, 1) void rbf_fallback_kernel(
    const float* __restrict__ x,
    const float* __restrict__ centers,
    const float* __restrict__ log_sigmas,
    float* __restrict__ out)
{
    __shared__ u32x4 sC[ODIM * 16];
    __shared__ float sIS[ODIM];
    __shared__ float sCS[ODIM];

    const int t  = threadIdx.x;
    const int w  = t >> 6;
    const int l  = t & 63;
    const int lr = l & 15;
    const int lk = l >> 4;

    #pragma unroll
    for (int i = 0; i < 8; ++i) {
        int c    = i * 1024 + t;
        int row  = c >> 4;
        int col8 = c & 15;
        const f32x4* gp = (const f32x4*)(centers + (size_t)row * KDIM + col8 * 8);
        f32x4 v0 = gp[0], v1 = gp[1];
        float s = v0.x*v0.x + v0.y*v0.y + v0.z*v0.z + v0.w*v0.w
                + v1.x*v1.x + v1.y*v1.y + v1.z*v1.z + v1.w*v1.w;
        s += __shfl_xor(s, 1); s += __shfl_xor(s, 2);
        s += __shfl_xor(s, 4); s += __shfl_xor(s, 8);
        BF8 wv;
        wv.u[0] = pack_bf2(v0.x, v0.y);
        wv.u[1] = pack_bf2(v0.z, v0.w);
        wv.u[2] = pack_bf2(v1.x, v1.y);
        wv.u[3] = pack_bf2(v1.z, v1.w);
        int byte = row * 256 + col8 * 16;
        byte ^= (row & 7) << 4;
        *(u32x4*)((char*)sC + byte) = wv.q;
        if ((t & 15) == 0) {
            float a = __expf(-2.0f * log_sigmas[row]);
            sIS[row] = a;
            sCS[row] = s * a;
        }
    }
    __syncthreads();

    const int r0 = blockIdx.x * 512 + w * 32;
    bf16x8 xf[2][4];
    float  xsq[2];
    #pragma unroll
    for (int tt = 0; tt < 2; ++tt) {
        const float* xp = x + (size_t)(r0 + tt * 16 + lr) * KDIM + lk * 8;
        float s = 0.f;
        #pragma unroll
        for (int kk = 0; kk < 4; ++kk) {
            const f32x4* p = (const f32x4*)(xp + kk * 32);
            f32x4 v0 = p[0], v1 = p[1];
            s += v0.x*v0.x + v0.y*v0.y + v0.z*v0.z + v0.w*v0.w
               + v1.x*v1.x + v1.y*v1.y + v1.z*v1.z + v1.w*v1.w;
            BF8 b;
            b.u[0] = pack_bf2(v0.x, v0.y);
            b.u[1] = pack_bf2(v0.z, v0.w);
            b.u[2] = pack_bf2(v1.x, v1.y);
            b.u[3] = pack_bf2(v1.z, v1.w);
            xf[tt][kk] = b.v;
        }
        s += __shfl_xor(s, 16);
        s += __shfl_xor(s, 32);
        xsq[tt] = s;
    }

    float* orow0 = out + (size_t)(r0 + lr) * ODIM;
    float* orow1 = out + (size_t)(r0 + 16 + lr) * ODIM;

    #pragma unroll 2
    for (int g = 0; g < 32; ++g) {
        bf16x8 af[4];
        #pragma unroll
        for (int kk = 0; kk < 4; ++kk) {
            int row  = g * 16 + lr;
            int byte = row * 256 + kk * 64 + lk * 16;
            byte ^= (row & 7) << 4;
            af[kk] = *(const bf16x8*)((const char*)sC + byte);
        }
        f32x4 a0 = (f32x4){0.f, 0.f, 0.f, 0.f};
        f32x4 a1 = (f32x4){0.f, 0.f, 0.f, 0.f};
        #pragma unroll
        for (int kk = 0; kk < 4; ++kk) {
            a0 = __builtin_amdgcn_mfma_f32_16x16x32_bf16(af[kk], xf[0][kk], a0, 0, 0, 0);
            a1 = __builtin_amdgcn_mfma_f32_16x16x32_bf16(af[kk], xf[1][kk], a1, 0, 0, 0);
        }
        const int cb = g * 16 + lk * 4;
        f32x4 A4 = *(const f32x4*)&sIS[cb];
        f32x4 B4 = *(const f32x4*)&sCS[cb];
        f32x4 o0, o1;
        o0.x = __expf(-fmaxf(fmaf(A4.x, fmaf(-2.f, a0[0], xsq[0]), B4.x), 0.f));
        o0.y = __expf(-fmaxf(fmaf(A4.y, fmaf(-2.f, a0[1], xsq[0]), B4.y), 0.f));
        o0.z = __expf(-fmaxf(fmaf(A4.z, fmaf(-2.f, a0[2], xsq[0]), B4.z), 0.f));
        o0.w = __expf(-fmaxf(fmaf(A4.w, fmaf(-2.f, a0[3], xsq[0]), B4.w), 0.f));
        o1.x = __expf(-fmaxf(fmaf(A4.x, fmaf(-2.f, a1[0], xsq[1]), B4.x), 0.f));
        o1.y = __expf(-fmaxf(fmaf(A4.y, fmaf(-2.f, a1[1], xsq[1]), B4.y), 0.f));
        o1.z = __expf(-fmaxf(fmaf(A4.z, fmaf(-2.f, a1[2], xsq[1]), B4.z), 0.f));
        o1.w = __expf(-fmaxf(fmaf(A4.w, fmaf(-2.f, a1[3], xsq[1]), B4.w), 0.f));
        *(f32x4*)(orow0 + cb) = o0;
        *(f32x4*)(orow1 + cb) = o1;
    }
}

extern "C" void kernel_launch(void* const* d_in, const int* in_sizes, int n_in,
                              void* d_out, int out_size, void* d_ws, size_t ws_size,
                              hipStream_t stream) {
    const float* x          = (const float*)d_in[0];
    const float* centers    = (const float*)d_in[1];
    const float* log_sigmas = (const float*)d_in[2];
    float* out = (float*)d_out;

    const int n_rows = in_sizes[0] / KDIM;   // 131072

    // ws layout: 128KiB frags + 2KiB sIS + 2KiB sCS
    const size_t WS_NEED = 128 * 1024 + 2 * 2048;
    if (ws_size >= WS_NEED) {
        u32x4* wsfrag = (u32x4*)d_ws;
        float* wsis   = (float*)((char*)d_ws + 128 * 1024);
        float* wscs   = (float*)((char*)d_ws + 128 * 1024 + 2048);
        rbf_pack_kernel<<<34, 256, 0, stream>>>(centers, log_sigmas,
                                                wsfrag, wsis, wscs);
        rbf_main_kernel<<<n_rows / 128, 256, 0, stream>>>(
            x, wsfrag, (const f32x4*)wsis, (const f32x4*)wscs, out);
    } else {
        rbf_fallback_kernel<<<n_rows / 512, 1024, 0, stream>>>(
            x, centers, log_sigmas, out);
    }
}

// Round 7
// 92.188 us; speedup vs baseline: 1.1912x; 1.1912x over previous
//
#include <hip/hip_runtime.h>
#include <hip/hip_bf16.h>

// RBF: out[n][o] = exp(-max(||x_n||^2 - 2<x_n,c_o> + ||c_o||^2, 0) * exp(-2*ls_o))
// M=131072, K=128, O=512.  Memory-bound: 67MB read + 268MB write -> ~55us floor.
//
// Round-7: R3 structure (256 blocks x 16 waves, all centers in LDS, 1 barrier,
// plain loads/stores) with the LDS bank-conflict fix:
//   R3's XOR swizzle folded lk into the same byte bits -> 8-way conflict on
//   every ds_read_b128 (~30us/CU serialized LDS). Now K1 packs centers into
//   d_ws in EXACT fragment order; K2 copies it lane-linearly into LDS, and the
//   in-loop read is lds[(g*4+kk)*64 + l] -> 64 consecutive 16-B chunks per
//   instruction = ZERO bank conflicts, on both copy and reads.
// Also: log2e folded into K1 tables -> exp2f epilogue (one v_mul saved/elem).

typedef __attribute__((ext_vector_type(8))) short bf16x8;
typedef __attribute__((ext_vector_type(4))) float f32x4;
typedef __attribute__((ext_vector_type(4))) unsigned u32x4;

#define KDIM 128
#define ODIM 512
#define LOG2E 1.4426950408889634f

union BF8 { unsigned u[4]; bf16x8 v; u32x4 q; };

// round-to-nearest-even fp32 -> bf16, packed pair
__device__ __forceinline__ unsigned pack_bf2(float a, float b) {
    unsigned ua = __builtin_bit_cast(unsigned, a);
    unsigned ub = __builtin_bit_cast(unsigned, b);
    ua += 0x7fffu + ((ua >> 16) & 1u);
    ub += 0x7fffu + ((ub >> 16) & 1u);
    return (ua >> 16) | (ub & 0xffff0000u);
}

// ---------------- K1: pack centers + tables into ws ----------------
// ws layout: [0,128KiB) frag region: u32x4 index (g*4+kk)*64+l holds bf16x8 of
//            center c=g*16+(l&15), k = kk*32+(l>>4)*8 .. +8
//            [128KiB,+2KiB) wsis = exp(-2*ls)*log2e
//            [130KiB,+2KiB) wscs = csq*exp(-2*ls)*log2e
__global__ __launch_bounds__(256) void rbf_pack_kernel(
    const float* __restrict__ centers,
    const float* __restrict__ log_sigmas,
    u32x4* __restrict__ wsfrag,
    float* __restrict__ wsis,
    float* __restrict__ wscs)
{
    const int b = blockIdx.x;
    if (b < 32) {
        int i  = b * 256 + threadIdx.x;      // 0..8191
        int g  = i >> 8;
        int kk = (i >> 6) & 3;
        int l  = i & 63;
        int c  = g * 16 + (l & 15);
        int k0 = kk * 32 + (l >> 4) * 8;
        const f32x4* p = (const f32x4*)(centers + (size_t)c * KDIM + k0);
        f32x4 v0 = p[0], v1 = p[1];
        BF8 w;
        w.u[0] = pack_bf2(v0.x, v0.y);
        w.u[1] = pack_bf2(v0.z, v0.w);
        w.u[2] = pack_bf2(v1.x, v1.y);
        w.u[3] = pack_bf2(v1.z, v1.w);
        wsfrag[i] = w.q;
    } else {
        int c = (b - 32) * 256 + threadIdx.x;   // 0..511
        const f32x4* p = (const f32x4*)(centers + (size_t)c * KDIM);
        float s = 0.f;
        #pragma unroll
        for (int k = 0; k < 32; ++k) {
            f32x4 v = p[k];
            s += v.x*v.x + v.y*v.y + v.z*v.z + v.w*v.w;
        }
        float a = __expf(-2.0f * log_sigmas[c]) * LOG2E;
        wsis[c] = a;
        wscs[c] = s * a;
    }
}

// ---------------- K2: main kernel ----------------
__global__ __launch_bounds__(1024, 4) void rbf_main_kernel(
    const float* __restrict__ x,
    const u32x4* __restrict__ wsfrag,
    const f32x4* __restrict__ wsis4,
    const f32x4* __restrict__ wscs4,
    float* __restrict__ out)
{
    __shared__ u32x4 sF[8192];   // 128 KiB, lane-linear fragment order
    __shared__ float sIS[ODIM];  // 2 KiB
    __shared__ float sCS[ODIM];  // 2 KiB

    const int t  = threadIdx.x;  // 0..1023
    const int w  = t >> 6;       // wave 0..15
    const int l  = t & 63;
    const int lr = l & 15;       // x-row within tile (C/D col)
    const int lk = l >> 4;       // k-group / center sub-block

    // ---- copy frag table + tables into LDS (conflict-free both sides) ----
    #pragma unroll
    for (int i = 0; i < 8; ++i)
        sF[i * 1024 + t] = wsfrag[i * 1024 + t];
    if (t < 128) {
        ((f32x4*)sIS)[t] = wsis4[t];
        ((f32x4*)sCS)[t] = wscs4[t];
    }
    __syncthreads();   // the only barrier

    // ---- this wave's 32 x-rows -> bf16 register fragments (2 tiles) ----
    const int r0 = blockIdx.x * 512 + w * 32;
    bf16x8 xf0[4], xf1[4];
    float xsq0, xsq1;
#define LOADX(XF, XS, ROWOFF)                                                  \
    {                                                                          \
        const float* xp = x + (size_t)(r0 + (ROWOFF) + lr) * KDIM + lk * 8;    \
        float s = 0.f;                                                         \
        _Pragma("unroll")                                                      \
        for (int kk = 0; kk < 4; ++kk) {                                       \
            const f32x4* p = (const f32x4*)(xp + kk * 32);                     \
            f32x4 v0 = p[0], v1 = p[1];                                        \
            s += v0.x*v0.x + v0.y*v0.y + v0.z*v0.z + v0.w*v0.w                 \
               + v1.x*v1.x + v1.y*v1.y + v1.z*v1.z + v1.w*v1.w;                \
            BF8 bw;                                                            \
            bw.u[0] = pack_bf2(v0.x, v0.y);                                    \
            bw.u[1] = pack_bf2(v0.z, v0.w);                                    \
            bw.u[2] = pack_bf2(v1.x, v1.y);                                    \
            bw.u[3] = pack_bf2(v1.z, v1.w);                                    \
            XF[kk] = bw.v;                                                     \
        }                                                                      \
        s += __shfl_xor(s, 16);                                                \
        s += __shfl_xor(s, 32);                                                \
        XS = s;                                                                \
    }
    LOADX(xf0, xsq0, 0)
    LOADX(xf1, xsq1, 16)
#undef LOADX

    float* orow0 = out + (size_t)(r0 + lr) * ODIM;
    float* orow1 = orow0 + (size_t)16 * ODIM;

    const bf16x8* fB = (const bf16x8*)sF + l;   // + (g*4+kk)*64

    // ---- main loop: 32 groups of 16 centers ----
    #pragma unroll 2
    for (int g = 0; g < 32; ++g) {
        f32x4 a0 = (f32x4){0.f, 0.f, 0.f, 0.f};
        f32x4 a1 = (f32x4){0.f, 0.f, 0.f, 0.f};
        #pragma unroll
        for (int kk = 0; kk < 4; ++kk) {
            bf16x8 cf = fB[(g * 4 + kk) * 64];   // lane-linear: zero conflicts
            a0 = __builtin_amdgcn_mfma_f32_16x16x32_bf16(cf, xf0[kk], a0, 0, 0, 0);
            a1 = __builtin_amdgcn_mfma_f32_16x16x32_bf16(cf, xf1[kk], a1, 0, 0, 0);
        }
        // lane owns centers cb..cb+3 (consecutive), x-rows (r0+lr), (r0+16+lr)
        const int cb = g * 16 + lk * 4;
        f32x4 A4 = *(const f32x4*)&sIS[cb];   // pre-scaled by log2e
        f32x4 B4 = *(const f32x4*)&sCS[cb];
        f32x4 o0, o1;
        o0.x = exp2f(-fmaxf(fmaf(A4.x, fmaf(-2.f, a0[0], xsq0), B4.x), 0.f));
        o0.y = exp2f(-fmaxf(fmaf(A4.y, fmaf(-2.f, a0[1], xsq0), B4.y), 0.f));
        o0.z = exp2f(-fmaxf(fmaf(A4.z, fmaf(-2.f, a0[2], xsq0), B4.z), 0.f));
        o0.w = exp2f(-fmaxf(fmaf(A4.w, fmaf(-2.f, a0[3], xsq0), B4.w), 0.f));
        o1.x = exp2f(-fmaxf(fmaf(A4.x, fmaf(-2.f, a1[0], xsq1), B4.x), 0.f));
        o1.y = exp2f(-fmaxf(fmaf(A4.y, fmaf(-2.f, a1[1], xsq1), B4.y), 0.f));
        o1.z = exp2f(-fmaxf(fmaf(A4.z, fmaf(-2.f, a1[2], xsq1), B4.z), 0.f));
        o1.w = exp2f(-fmaxf(fmaf(A4.w, fmaf(-2.f, a1[3], xsq1), B4.w), 0.f));
        *(f32x4*)(orow0 + cb) = o0;
        *(f32x4*)(orow1 + cb) = o1;
    }
}

// ---------------- fallback (round-3 kernel, proven): used if ws too small ----
__global__ __launch_bounds__(1024, 1) void rbf_fallback_kernel(
    const float* __restrict__ x,
    const float* __restrict__ centers,
    const float* __restrict__ log_sigmas,
    float* __restrict__ out)
{
    __shared__ u32x4 sC[ODIM * 16];
    __shared__ float sIS[ODIM];
    __shared__ float sCS[ODIM];

    const int t  = threadIdx.x;
    const int w  = t >> 6;
    const int l  = t & 63;
    const int lr = l & 15;
    const int lk = l >> 4;

    #pragma unroll
    for (int i = 0; i < 8; ++i) {
        int c    = i * 1024 + t;
        int row  = c >> 4;
        int col8 = c & 15;
        const f32x4* gp = (const f32x4*)(centers + (size_t)row * KDIM + col8 * 8);
        f32x4 v0 = gp[0], v1 = gp[1];
        float s = v0.x*v0.x + v0.y*v0.y + v0.z*v0.z + v0.w*v0.w
                + v1.x*v1.x + v1.y*v1.y + v1.z*v1.z + v1.w*v1.w;
        s += __shfl_xor(s, 1); s += __shfl_xor(s, 2);
        s += __shfl_xor(s, 4); s += __shfl_xor(s, 8);
        BF8 wv;
        wv.u[0] = pack_bf2(v0.x, v0.y);
        wv.u[1] = pack_bf2(v0.z, v0.w);
        wv.u[2] = pack_bf2(v1.x, v1.y);
        wv.u[3] = pack_bf2(v1.z, v1.w);
        int byte = row * 256 + col8 * 16;
        byte ^= (row & 7) << 4;
        *(u32x4*)((char*)sC + byte) = wv.q;
        if ((t & 15) == 0) {
            float a = __expf(-2.0f * log_sigmas[row]);
            sIS[row] = a;
            sCS[row] = s * a;
        }
    }
    __syncthreads();

    const int r0 = blockIdx.x * 512 + w * 32;
    bf16x8 xf[2][4];
    float  xsq[2];
    #pragma unroll
    for (int tt = 0; tt < 2; ++tt) {
        const float* xp = x + (size_t)(r0 + tt * 16 + lr) * KDIM + lk * 8;
        float s = 0.f;
        #pragma unroll
        for (int kk = 0; kk < 4; ++kk) {
            const f32x4* p = (const f32x4*)(xp + kk * 32);
            f32x4 v0 = p[0], v1 = p[1];
            s += v0.x*v0.x + v0.y*v0.y + v0.z*v0.z + v0.w*v0.w
               + v1.x*v1.x + v1.y*v1.y + v1.z*v1.z + v1.w*v1.w;
            BF8 b;
            b.u[0] = pack_bf2(v0.x, v0.y);
            b.u[1] = pack_bf2(v0.z, v0.w);
            b.u[2] = pack_bf2(v1.x, v1.y);
            b.u[3] = pack_bf2(v1.z, v1.w);
            xf[tt][kk] = b.v;
        }
        s += __shfl_xor(s, 16);
        s += __shfl_xor(s, 32);
        xsq[tt] = s;
    }

    float* orow0 = out + (size_t)(r0 + lr) * ODIM;
    float* orow1 = out + (size_t)(r0 + 16 + lr) * ODIM;

    #pragma unroll 2
    for (int g = 0; g < 32; ++g) {
        bf16x8 af[4];
        #pragma unroll
        for (int kk = 0; kk < 4; ++kk) {
            int row  = g * 16 + lr;
            int byte = row * 256 + kk * 64 + lk * 16;
            byte ^= (row & 7) << 4;
            af[kk] = *(const bf16x8*)((const char*)sC + byte);
        }
        f32x4 a0 = (f32x4){0.f, 0.f, 0.f, 0.f};
        f32x4 a1 = (f32x4){0.f, 0.f, 0.f, 0.f};
        #pragma unroll
        for (int kk = 0; kk < 4; ++kk) {
            a0 = __builtin_amdgcn_mfma_f32_16x16x32_bf16(af[kk], xf[0][kk], a0, 0, 0, 0);
            a1 = __builtin_amdgcn_mfma_f32_16x16x32_bf16(af[kk], xf[1][kk], a1, 0, 0, 0);
        }
        const int cb = g * 16 + lk * 4;
        f32x4 A4 = *(const f32x4*)&sIS[cb];
        f32x4 B4 = *(const f32x4*)&sCS[cb];
        f32x4 o0, o1;
        o0.x = __expf(-fmaxf(fmaf(A4.x, fmaf(-2.f, a0[0], xsq[0]), B4.x), 0.f));
        o0.y = __expf(-fmaxf(fmaf(A4.y, fmaf(-2.f, a0[1], xsq[0]), B4.y), 0.f));
        o0.z = __expf(-fmaxf(fmaf(A4.z, fmaf(-2.f, a0[2], xsq[0]), B4.z), 0.f));
        o0.w = __expf(-fmaxf(fmaf(A4.w, fmaf(-2.f, a0[3], xsq[0]), B4.w), 0.f));
        o1.x = __expf(-fmaxf(fmaf(A4.x, fmaf(-2.f, a1[0], xsq[1]), B4.x), 0.f));
        o1.y = __expf(-fmaxf(fmaf(A4.y, fmaf(-2.f, a1[1], xsq[1]), B4.y), 0.f));
        o1.z = __expf(-fmaxf(fmaf(A4.z, fmaf(-2.f, a1[2], xsq[1]), B4.z), 0.f));
        o1.w = __expf(-fmaxf(fmaf(A4.w, fmaf(-2.f, a1[3], xsq[1]), B4.w), 0.f));
        *(f32x4*)(orow0 + cb) = o0;
        *(f32x4*)(orow1 + cb) = o1;
    }
}

extern "C" void kernel_launch(void* const* d_in, const int* in_sizes, int n_in,
                              void* d_out, int out_size, void* d_ws, size_t ws_size,
                              hipStream_t stream) {
    const float* x          = (const float*)d_in[0];
    const float* centers    = (const float*)d_in[1];
    const float* log_sigmas = (const float*)d_in[2];
    float* out = (float*)d_out;

    const int n_rows = in_sizes[0] / KDIM;   // 131072

    // ws layout: 128KiB frags + 2KiB wsis + 2KiB wscs
    const size_t WS_NEED = 128 * 1024 + 2 * 2048;
    if (ws_size >= WS_NEED) {
        u32x4* wsfrag = (u32x4*)d_ws;
        float* wsis   = (float*)((char*)d_ws + 128 * 1024);
        float* wscs   = (float*)((char*)d_ws + 128 * 1024 + 2048);
        rbf_pack_kernel<<<34, 256, 0, stream>>>(centers, log_sigmas,
                                                wsfrag, wsis, wscs);
        rbf_main_kernel<<<n_rows / 512, 1024, 0, stream>>>(
            x, wsfrag, (const f32x4*)wsis, (const f32x4*)wscs, out);
    } else {
        rbf_fallback_kernel<<<n_rows / 512, 1024, 0, stream>>>(
            x, centers, log_sigmas, out);
    }
}

// Round 8
// 86.460 us; speedup vs baseline: 1.2701x; 1.0663x over previous
//
#include <hip/hip_runtime.h>
#include <hip/hip_bf16.h>

// RBF: out[n][o] = exp(-max(||x_n||^2 - 2<x_n,c_o> + ||c_o||^2, 0) * exp(-2*ls_o))
// M=131072, K=128, O=512.  Memory floor ~52us (67MB read + 268MB write @6.5TB/s).
//
// Round-8: attack the 64B-partial-line store pattern (shared by ALL prior
// rounds; explains the ~92us plateau as write RFO / page-locality overhead).
//  K1: pack centers bf16-fragments + fused tables into d_ws (unchanged).
//  K2: 1024 blocks x 4 waves, 4 blocks/CU, ZERO barriers.
//      - center frags double-buffer-prefetched from L2-resident ws
//      - per 4 center-groups: stage 32rows x 64cols fp32 into a WAVE-PRIVATE
//        8KB LDS buffer (chunk XOR row swizzle -> conflict-free b128 both
//        sides), then drain as 8 store instrs, each 8 rows x 128B FULL LINES
//        (256B-aligned). No partial-line HBM writes anywhere.

typedef __attribute__((ext_vector_type(8))) short bf16x8;
typedef __attribute__((ext_vector_type(4))) float f32x4;
typedef __attribute__((ext_vector_type(4))) unsigned u32x4;

#define KDIM 128
#define ODIM 512
#define LOG2E 1.4426950408889634f

union BF8 { unsigned u[4]; bf16x8 v; u32x4 q; };

// round-to-nearest-even fp32 -> bf16, packed pair
__device__ __forceinline__ unsigned pack_bf2(float a, float b) {
    unsigned ua = __builtin_bit_cast(unsigned, a);
    unsigned ub = __builtin_bit_cast(unsigned, b);
    ua += 0x7fffu + ((ua >> 16) & 1u);
    ub += 0x7fffu + ((ub >> 16) & 1u);
    return (ua >> 16) | (ub & 0xffff0000u);
}

// ---------------- K1: pack centers + tables into ws ----------------
// ws layout: [0,128KiB) frag region: u32x4 index (g*4+kk)*64+l holds bf16x8 of
//            center c=g*16+(l&15), k = kk*32+(l>>4)*8 .. +8
//            [128KiB,+2KiB) wsis = exp(-2*ls)*log2e
//            [130KiB,+2KiB) wscs = csq*exp(-2*ls)*log2e
__global__ __launch_bounds__(256) void rbf_pack_kernel(
    const float* __restrict__ centers,
    const float* __restrict__ log_sigmas,
    u32x4* __restrict__ wsfrag,
    float* __restrict__ wsis,
    float* __restrict__ wscs)
{
    const int b = blockIdx.x;
    if (b < 32) {
        int i  = b * 256 + threadIdx.x;      // 0..8191
        int g  = i >> 8;
        int kk = (i >> 6) & 3;
        int l  = i & 63;
        int c  = g * 16 + (l & 15);
        int k0 = kk * 32 + (l >> 4) * 8;
        const f32x4* p = (const f32x4*)(centers + (size_t)c * KDIM + k0);
        f32x4 v0 = p[0], v1 = p[1];
        BF8 w;
        w.u[0] = pack_bf2(v0.x, v0.y);
        w.u[1] = pack_bf2(v0.z, v0.w);
        w.u[2] = pack_bf2(v1.x, v1.y);
        w.u[3] = pack_bf2(v1.z, v1.w);
        wsfrag[i] = w.q;
    } else {
        int c = (b - 32) * 256 + threadIdx.x;   // 0..511
        const f32x4* p = (const f32x4*)(centers + (size_t)c * KDIM);
        float s = 0.f;
        #pragma unroll
        for (int k = 0; k < 32; ++k) {
            f32x4 v = p[k];
            s += v.x*v.x + v.y*v.y + v.z*v.z + v.w*v.w;
        }
        float a = __expf(-2.0f * log_sigmas[c]) * LOG2E;
        wsis[c] = a;
        wscs[c] = s * a;
    }
}

// ---------------- K2: main kernel ----------------
__global__ __launch_bounds__(256, 4) void rbf_main_kernel(
    const float* __restrict__ x,
    const u32x4* __restrict__ wsfrag,
    const f32x4* __restrict__ wsis4,
    const f32x4* __restrict__ wscs4,
    float* __restrict__ out)
{
    // per-wave private staging: 32 rows x 16 chunks(16B) = 8KB; 4 waves = 32KB
    __shared__ f32x4 stage[4][32 * 16];

    const int t  = threadIdx.x;   // 0..255
    const int w  = t >> 6;        // wave 0..3
    const int l  = t & 63;
    const int lr = l & 15;        // x-row within 16-row tile (C/D col)
    const int lk = l >> 4;        // k-group / center sub-block

    const int r0 = blockIdx.x * 128 + w * 32;   // this wave's 32 rows

    // ---- x -> bf16 register fragments (2 x 16-row tiles) ----
    bf16x8 xf0[4], xf1[4];
    float xsq0, xsq1;
#define LOADX(XF, XS, ROWOFF)                                                  \
    {                                                                          \
        const float* xp = x + (size_t)(r0 + (ROWOFF) + lr) * KDIM + lk * 8;    \
        float s = 0.f;                                                         \
        _Pragma("unroll")                                                      \
        for (int kk = 0; kk < 4; ++kk) {                                       \
            const f32x4* p = (const f32x4*)(xp + kk * 32);                     \
            f32x4 v0 = p[0], v1 = p[1];                                        \
            s += v0.x*v0.x + v0.y*v0.y + v0.z*v0.z + v0.w*v0.w                 \
               + v1.x*v1.x + v1.y*v1.y + v1.z*v1.z + v1.w*v1.w;                \
            BF8 bw;                                                            \
            bw.u[0] = pack_bf2(v0.x, v0.y);                                    \
            bw.u[1] = pack_bf2(v0.z, v0.w);                                    \
            bw.u[2] = pack_bf2(v1.x, v1.y);                                    \
            bw.u[3] = pack_bf2(v1.z, v1.w);                                    \
            XF[kk] = bw.v;                                                     \
        }                                                                      \
        s += __shfl_xor(s, 16);                                                \
        s += __shfl_xor(s, 32);                                                \
        XS = s;                                                                \
    }
    LOADX(xf0, xsq0, 0)
    LOADX(xf1, xsq1, 16)
#undef LOADX

    f32x4* st = &stage[w][0];                       // wave-private
    const bf16x8* fb = (const bf16x8*)wsfrag + l;   // + (g*4+kk)*64

    // preload group-0 fragments (L2-resident)
    bf16x8 cfA[4], cfB[4];
    cfA[0] = fb[0];
    cfA[1] = fb[64];
    cfA[2] = fb[128];
    cfA[3] = fb[192];

    // one center-group: prefetch next frags, 8 MFMA, epilogue, 2 swizzled
    // ds_writes into the wave-private stage (chunk ^ row -> conflict-free b128)
#define STEP(G, T, CUR, NXT)                                                   \
    {                                                                          \
        const int gn = ((G) + 1) & 31;                                         \
        NXT[0] = fb[gn * 256 + 0];                                             \
        NXT[1] = fb[gn * 256 + 64];                                            \
        NXT[2] = fb[gn * 256 + 128];                                           \
        NXT[3] = fb[gn * 256 + 192];                                           \
        f32x4 a0 = (f32x4){0.f, 0.f, 0.f, 0.f};                                \
        f32x4 a1 = (f32x4){0.f, 0.f, 0.f, 0.f};                                \
        _Pragma("unroll")                                                      \
        for (int kk = 0; kk < 4; ++kk) {                                       \
            a0 = __builtin_amdgcn_mfma_f32_16x16x32_bf16(CUR[kk], xf0[kk], a0, 0, 0, 0); \
            a1 = __builtin_amdgcn_mfma_f32_16x16x32_bf16(CUR[kk], xf1[kk], a1, 0, 0, 0); \
        }                                                                      \
        const int gi = (G) * 4 + lk;                                           \
        f32x4 A4 = wsis4[gi];                                                  \
        f32x4 B4 = wscs4[gi];                                                  \
        f32x4 o0, o1;                                                          \
        o0.x = exp2f(-fmaxf(fmaf(A4.x, fmaf(-2.f, a0[0], xsq0), B4.x), 0.f));  \
        o0.y = exp2f(-fmaxf(fmaf(A4.y, fmaf(-2.f, a0[1], xsq0), B4.y), 0.f));  \
        o0.z = exp2f(-fmaxf(fmaf(A4.z, fmaf(-2.f, a0[2], xsq0), B4.z), 0.f));  \
        o0.w = exp2f(-fmaxf(fmaf(A4.w, fmaf(-2.f, a0[3], xsq0), B4.w), 0.f));  \
        o1.x = exp2f(-fmaxf(fmaf(A4.x, fmaf(-2.f, a1[0], xsq1), B4.x), 0.f));  \
        o1.y = exp2f(-fmaxf(fmaf(A4.y, fmaf(-2.f, a1[1], xsq1), B4.y), 0.f));  \
        o1.z = exp2f(-fmaxf(fmaf(A4.z, fmaf(-2.f, a1[2], xsq1), B4.z), 0.f));  \
        o1.w = exp2f(-fmaxf(fmaf(A4.w, fmaf(-2.f, a1[3], xsq1), B4.w), 0.f));  \
        const int ch = ((T) * 4 + lk) ^ lr;   /* chunk XOR row swizzle */      \
        st[lr * 16 + ch]        = o0;         /* rows 0..15  */                \
        st[(16 + lr) * 16 + ch] = o1;         /* rows 16..31 (same ^lr) */     \
    }

    // ---- 8 super-iters: 4 groups staged, then full-line drain ----
    #pragma unroll 1
    for (int G0 = 0; G0 < 32; G0 += 4) {
        STEP(G0 + 0, 0, cfA, cfB)
        STEP(G0 + 1, 1, cfB, cfA)
        STEP(G0 + 2, 2, cfA, cfB)
        STEP(G0 + 3, 3, cfB, cfA)

        // drain: 8 instrs, each 8 rows x 128B contiguous (full cache lines),
        // row-span byte base G0*64 is 256B-aligned (G0 % 4 == 0).
        #pragma unroll
        for (int q = 0; q < 8; ++q) {
            int row = (q & 3) * 8 + (l >> 3);       // 0..31
            int c   = (q >> 2) * 8 + (l & 7);       // 0..15
            f32x4 v = st[row * 16 + (c ^ (row & 15))];
            float* op = out + (size_t)(r0 + row) * ODIM + G0 * 16 + c * 4;
            *(f32x4*)op = v;
        }
    }
#undef STEP
}

// ---------------- fallback (proven ~92us path): used if ws too small ----
__global__ __launch_bounds__(1024, 1) void rbf_fallback_kernel(
    const float* __restrict__ x,
    const float* __restrict__ centers,
    const float* __restrict__ log_sigmas,
    float* __restrict__ out)
{
    __shared__ u32x4 sC[ODIM * 16];
    __shared__ float sIS[ODIM];
    __shared__ float sCS[ODIM];

    const int t  = threadIdx.x;
    const int w  = t >> 6;
    const int l  = t & 63;
    const int lr = l & 15;
    const int lk = l >> 4;

    #pragma unroll
    for (int i = 0; i < 8; ++i) {
        int c    = i * 1024 + t;
        int row  = c >> 4;
        int col8 = c & 15;
        const f32x4* gp = (const f32x4*)(centers + (size_t)row * KDIM + col8 * 8);
        f32x4 v0 = gp[0], v1 = gp[1];
        float s = v0.x*v0.x + v0.y*v0.y + v0.z*v0.z + v0.w*v0.w
                + v1.x*v1.x + v1.y*v1.y + v1.z*v1.z + v1.w*v1.w;
        s += __shfl_xor(s, 1); s += __shfl_xor(s, 2);
        s += __shfl_xor(s, 4); s += __shfl_xor(s, 8);
        BF8 wv;
        wv.u[0] = pack_bf2(v0.x, v0.y);
        wv.u[1] = pack_bf2(v0.z, v0.w);
        wv.u[2] = pack_bf2(v1.x, v1.y);
        wv.u[3] = pack_bf2(v1.z, v1.w);
        int byte = row * 256 + col8 * 16;
        byte ^= (row & 7) << 4;
        *(u32x4*)((char*)sC + byte) = wv.q;
        if ((t & 15) == 0) {
            float a = __expf(-2.0f * log_sigmas[row]);
            sIS[row] = a;
            sCS[row] = s * a;
        }
    }
    __syncthreads();

    const int r0 = blockIdx.x * 512 + w * 32;
    bf16x8 xf[2][4];
    float  xsq[2];
    #pragma unroll
    for (int tt = 0; tt < 2; ++tt) {
        const float* xp = x + (size_t)(r0 + tt * 16 + lr) * KDIM + lk * 8;
        float s = 0.f;
        #pragma unroll
        for (int kk = 0; kk < 4; ++kk) {
            const f32x4* p = (const f32x4*)(xp + kk * 32);
            f32x4 v0 = p[0], v1 = p[1];
            s += v0.x*v0.x + v0.y*v0.y + v0.z*v0.z + v0.w*v0.w
               + v1.x*v1.x + v1.y*v1.y + v1.z*v1.z + v1.w*v1.w;
            BF8 b;
            b.u[0] = pack_bf2(v0.x, v0.y);
            b.u[1] = pack_bf2(v0.z, v0.w);
            b.u[2] = pack_bf2(v1.x, v1.y);
            b.u[3] = pack_bf2(v1.z, v1.w);
            xf[tt][kk] = b.v;
        }
        s += __shfl_xor(s, 16);
        s += __shfl_xor(s, 32);
        xsq[tt] = s;
    }

    float* orow0 = out + (size_t)(r0 + lr) * ODIM;
    float* orow1 = out + (size_t)(r0 + 16 + lr) * ODIM;

    #pragma unroll 2
    for (int g = 0; g < 32; ++g) {
        bf16x8 af[4];
        #pragma unroll
        for (int kk = 0; kk < 4; ++kk) {
            int row  = g * 16 + lr;
            int byte = row * 256 + kk * 64 + lk * 16;
            byte ^= (row & 7) << 4;
            af[kk] = *(const bf16x8*)((const char*)sC + byte);
        }
        f32x4 a0 = (f32x4){0.f, 0.f, 0.f, 0.f};
        f32x4 a1 = (f32x4){0.f, 0.f, 0.f, 0.f};
        #pragma unroll
        for (int kk = 0; kk < 4; ++kk) {
            a0 = __builtin_amdgcn_mfma_f32_16x16x32_bf16(af[kk], xf[0][kk], a0, 0, 0, 0);
            a1 = __builtin_amdgcn_mfma_f32_16x16x32_bf16(af[kk], xf[1][kk], a1, 0, 0, 0);
        }
        const int cb = g * 16 + lk * 4;
        f32x4 A4 = *(const f32x4*)&sIS[cb];
        f32x4 B4 = *(const f32x4*)&sCS[cb];
        f32x4 o0, o1;
        o0.x = __expf(-fmaxf(fmaf(A4.x, fmaf(-2.f, a0[0], xsq[0]), B4.x), 0.f));
        o0.y = __expf(-fmaxf(fmaf(A4.y, fmaf(-2.f, a0[1], xsq[0]), B4.y), 0.f));
        o0.z = __expf(-fmaxf(fmaf(A4.z, fmaf(-2.f, a0[2], xsq[0]), B4.z), 0.f));
        o0.w = __expf(-fmaxf(fmaf(A4.w, fmaf(-2.f, a0[3], xsq[0]), B4.w), 0.f));
        o1.x = __expf(-fmaxf(fmaf(A4.x, fmaf(-2.f, a1[0], xsq[1]), B4.x), 0.f));
        o1.y = __expf(-fmaxf(fmaf(A4.y, fmaf(-2.f, a1[1], xsq[1]), B4.y), 0.f));
        o1.z = __expf(-fmaxf(fmaf(A4.z, fmaf(-2.f, a1[2], xsq[1]), B4.z), 0.f));
        o1.w = __expf(-fmaxf(fmaf(A4.w, fmaf(-2.f, a1[3], xsq[1]), B4.w), 0.f));
        *(f32x4*)(orow0 + cb) = o0;
        *(f32x4*)(orow1 + cb) = o1;
    }
}

extern "C" void kernel_launch(void* const* d_in, const int* in_sizes, int n_in,
                              void* d_out, int out_size, void* d_ws, size_t ws_size,
                              hipStream_t stream) {
    const float* x          = (const float*)d_in[0];
    const float* centers    = (const float*)d_in[1];
    const float* log_sigmas = (const float*)d_in[2];
    float* out = (float*)d_out;

    const int n_rows = in_sizes[0] / KDIM;   // 131072

    // ws layout: 128KiB frags + 2KiB wsis + 2KiB wscs
    const size_t WS_NEED = 128 * 1024 + 2 * 2048;
    if (ws_size >= WS_NEED) {
        u32x4* wsfrag = (u32x4*)d_ws;
        float* wsis   = (float*)((char*)d_ws + 128 * 1024);
        float* wscs   = (float*)((char*)d_ws + 128 * 1024 + 2048);
        rbf_pack_kernel<<<34, 256, 0, stream>>>(centers, log_sigmas,
                                                wsfrag, wsis, wscs);
        rbf_main_kernel<<<n_rows / 128, 256, 0, stream>>>(
            x, wsfrag, (const f32x4*)wsis, (const f32x4*)wscs, out);
    } else {
        rbf_fallback_kernel<<<n_rows / 512, 1024, 0, stream>>>(
            x, centers, log_sigmas, out);
    }
}